// Round 5
// baseline (500.592 us; speedup 1.0000x reference)
//
#include <hip/hip_runtime.h>

#define N_NODES 100000
#define N_EDGES 1600000
#define IN_DIM 500
#define HID 32
#define N_REL 7
#define OUT_DIM 4
#define N_GRAPHS 16
#define NC 256      // (N_REL + 1) * HID: [root | rel0..rel6]
#define MC 224      // message cols (N_REL * HID)
#define KPAD 512

// dst-bucketing: 64 nodes/bucket; 8 sub-cursors/bucket (indexed blockIdx&7)
#define BK_SHIFT 6
#define BK_NODES 64
#define N_BUCKETS ((N_NODES + BK_NODES - 1) / BK_NODES)   // 1563
#define NSUB 8
#define SUB_CAP 256
#define BK_CAP (NSUB * SUB_CAP)  // 2048
#define NPOOL 8

typedef __attribute__((ext_vector_type(8))) short bf16x8;
typedef __attribute__((ext_vector_type(4))) float f32x4;

__device__ inline unsigned short f2bf(float f) {
    unsigned u = __float_as_uint(f);
    unsigned r = (u + 0x7FFFu + ((u >> 16) & 1u)) >> 16;
    return (unsigned short)r;
}
__device__ inline float bf2f(unsigned short b) {
    return __uint_as_float((unsigned)b << 16);
}

// ---------------- build Wbf: bf16 B-matrix in MFMA fragment order ----------
__global__ void build_wbf(const float* __restrict__ W_root,
                          const float* __restrict__ W_rel,
                          unsigned short* __restrict__ Wbf) {
    int idx = blockIdx.x * blockDim.x + threadIdx.x;   // 0 .. KPAD*NC-1
    if (idx >= KPAD * NC) return;
    int kk = idx >> 8;
    int n = idx & 255;
    float v = 0.f;
    if (kk < IN_DIM) {
        if (n < HID) v = W_root[kk * HID + n];
        else {
            int r = (n >> 5) - 1;
            v = W_rel[((size_t)r * IN_DIM + kk) * HID + (n & 31)];
        }
    }
    int ks = kk >> 5, q = (kk >> 3) & 3, j = kk & 7;
    Wbf[(size_t)((((ks << 2) + q) << 8) + n) * 8 + j] = f2bf(v);
}

// ---------------- MFMA GEMM v2: pipelined 4 K-chunks, double-buffered ------
// [Hr fp32 | Hm bf16] = bf16(A) @ Wbf. Tile 64 rows x 256 cols, 4 waves.
// Per chunk c: compute(c from LDS buf) || A-loads(c+2) in flight (reg-staged,
// T14: reg loads survive barriers); Wbf frags prefetched one ksl ahead.
__global__ __launch_bounds__(256, 3) void gemm_mfma(const float* __restrict__ A,
                                                    const uint4* __restrict__ Wbf,
                                                    float* __restrict__ Hr,
                                                    unsigned short* __restrict__ Hm) {
    __shared__ uint4 Alds[2][16 * 64];   // 2 x 16 KB: entry(ksq 0..15, row^swz)

    const int tid = threadIdx.x;
    const int wave = tid >> 6, lane = tid & 63;
    const int l16 = lane & 15, q = lane >> 4;
    const int row0 = blockIdx.x * 64;
    const int wn = wave * 64;

    int rows_valid = N_NODES - row0; if (rows_valid > 64) rows_valid = 64;
    const float4* Ablk4 = (const float4*)(A + (size_t)row0 * IN_DIM);

    // stage-reg mapping: j=0..7, idx=j*256+tid, row=idx>>5, slot=idx&31
    // chunk c covers k = c*128 + slot*4 .. +3
    float4 sreg[8];

    auto issue = [&](int c) {
        #pragma unroll
        for (int j = 0; j < 8; j++) {
            int idx = j * 256 + tid;
            int row = idx >> 5, slot = idx & 31;
            int k = c * 128 + slot * 4;
            float4 v = make_float4(0.f, 0.f, 0.f, 0.f);
            if (row < rows_valid && k < IN_DIM)
                v = Ablk4[row * 125 + (k >> 2)];
            sreg[j] = v;
        }
    };
    auto commit = [&](int c) {   // convert + LDS write into buf[c&1]
        #pragma unroll
        for (int j = 0; j < 8; j++) {
            int idx = j * 256 + tid;
            int row = idx >> 5, slot = idx & 31;
            int ksq = slot >> 1;                        // 0..15
            int e = (ksq << 6) | ((row ^ ksq) & 63);
            ushort4 b;
            b.x = f2bf(sreg[j].x); b.y = f2bf(sreg[j].y);
            b.z = f2bf(sreg[j].z); b.w = f2bf(sreg[j].w);
            *(ushort4*)((unsigned short*)&Alds[c & 1][e] + (slot & 1) * 4) = b;
        }
    };

    f32x4 acc[4][4];
    #pragma unroll
    for (int mt = 0; mt < 4; mt++)
        #pragma unroll
        for (int nt = 0; nt < 4; nt++)
            #pragma unroll
            for (int r = 0; r < 4; r++) acc[mt][nt][r] = 0.f;

    issue(0);
    commit(0);
    issue(1);
    __syncthreads();

    for (int c = 0; c < 4; c++) {
        // ---- compute chunk c from Alds[c&1], B prefetched one ksl ahead ----
        bf16x8 bnxt[4];
        {
            int kg = c * 16 + q;                        // ksl = 0
            #pragma unroll
            for (int nt = 0; nt < 4; nt++) {
                uint4 t = Wbf[(size_t)(kg << 8) + wn + nt * 16 + l16];
                bnxt[nt] = *(bf16x8*)&t;
            }
        }
        #pragma unroll
        for (int ksl = 0; ksl < 4; ksl++) {
            bf16x8 bcur[4];
            #pragma unroll
            for (int nt = 0; nt < 4; nt++) bcur[nt] = bnxt[nt];
            if (ksl < 3) {
                int kg = c * 16 + (ksl + 1) * 4 + q;
                #pragma unroll
                for (int nt = 0; nt < 4; nt++) {
                    uint4 t = Wbf[(size_t)(kg << 8) + wn + nt * 16 + l16];
                    bnxt[nt] = *(bf16x8*)&t;
                }
            }
            int ksq_l = ksl * 4 + q;
            bf16x8 afr[4];
            #pragma unroll
            for (int mt = 0; mt < 4; mt++)
                afr[mt] = *(const bf16x8*)&Alds[c & 1]
                    [(ksq_l << 6) | (((mt * 16 + l16) ^ ksq_l) & 63)];
            #pragma unroll
            for (int mt = 0; mt < 4; mt++)
                #pragma unroll
                for (int nt = 0; nt < 4; nt++)
                    acc[mt][nt] = __builtin_amdgcn_mfma_f32_16x16x32_bf16(
                        afr[mt], bcur[nt], acc[mt][nt], 0, 0, 0);
        }
        // ---- pipeline advance ----
        if (c < 3) {
            commit(c + 1);            // loads landed ~1 chunk ago
            if (c < 2) issue(c + 2);  // in flight across barrier + next compute
            __syncthreads();
        }
    }

    // ---- store: C/D layout col=lane&15, row=(lane>>4)*4+reg ----
    #pragma unroll
    for (int mt = 0; mt < 4; mt++) {
        int rbase = row0 + mt * 16 + q * 4;
        #pragma unroll
        for (int r = 0; r < 4; r++) {
            int row = rbase + r;
            if (row < N_NODES) {
                #pragma unroll
                for (int nt = 0; nt < 4; nt++) {
                    int col = wn + nt * 16 + l16;
                    float v = acc[mt][nt][r];
                    if (wave == 0 && nt < 2)            // col < 32: root slice
                        Hr[(size_t)row * HID + col] = v;
                    else
                        Hm[(size_t)row * MC + (col - HID)] = f2bf(v);
                }
            }
        }
    }
}

// ---------------- sub-cursor init ----------------
__global__ void init_bcur(int* __restrict__ bcur) {
    int i = blockIdx.x * blockDim.x + threadIdx.x;
    if (i < N_BUCKETS * NSUB) bcur[i] = i * SUB_CAP;
}

// ---------------- bin edges into (bucket, blockIdx&7) sub-regions ----------
__global__ __launch_bounds__(256) void bin_edges(const int* __restrict__ src,
                                                 const int* __restrict__ dst,
                                                 const int* __restrict__ attr,
                                                 int* __restrict__ bcur,
                                                 int* __restrict__ rec) {
    int e = blockIdx.x * blockDim.x + threadIdx.x;
    if (e >= N_EDGES) return;
    int d = dst[e];
    int cur = (d >> BK_SHIFT) * NSUB + (blockIdx.x & (NSUB - 1));
    int p = atomicAdd(&bcur[cur], 1);
    if (p < (cur + 1) * SUB_CAP)   // overflow guard (prob ~ 0)
        rec[p] = ((d & (BK_NODES - 1)) << 20) | (src[e] << 3) | attr[e];
}

// ---------------- per-bucket LDS counting sort + deg/offs/invcnt -----------
__global__ __launch_bounds__(256) void bucket_sort(int* __restrict__ rec,
                                                   const int* __restrict__ bcur,
                                                   int* __restrict__ deg,
                                                   int* __restrict__ offs,
                                                   float* __restrict__ invcnt) {
    __shared__ int h2[BK_NODES * N_REL];   // per-(node,rel) counts
    __shared__ int lcur[BK_NODES];         // scatter cursors
    __shared__ int sorted[BK_CAP];         // 8 KB
    __shared__ int scnt[NSUB];
    __shared__ int s_total;

    const int b = blockIdx.x, t = threadIdx.x;
    const int n0 = b << BK_SHIFT;
    const size_t rbase = (size_t)b * BK_CAP;

    for (int i = t; i < BK_NODES * N_REL; i += 256) h2[i] = 0;
    if (t < NSUB) {
        int c = bcur[b * NSUB + t] - (b * NSUB + t) * SUB_CAP;
        scnt[t] = c < SUB_CAP ? c : SUB_CAP;
    }
    __syncthreads();

    for (int s = 0; s < NSUB; s++) {
        int cs = scnt[s];
        const int* rp = rec + rbase + s * SUB_CAP;
        for (int i = t; i < cs; i += 256) {
            int q = rp[i];
            atomicAdd(&h2[(q >> 20) * N_REL + (q & 7)], 1);
        }
    }
    __syncthreads();

    if (t < BK_NODES) {       // wave 0: per-node totals + exclusive scan
        int tot = 0;
        #pragma unroll
        for (int r = 0; r < N_REL; r++) tot += h2[t * N_REL + r];
        int incl = tot;
        #pragma unroll
        for (int off = 1; off < BK_NODES; off <<= 1) {
            int y = __shfl_up(incl, off, 64);
            if (t >= off) incl += y;
        }
        int excl = incl - tot;
        lcur[t] = excl;
        if (t == BK_NODES - 1) s_total = incl;
        int n = n0 + t;
        if (n < N_NODES) {
            deg[n] = tot;
            offs[n] = (int)rbase + excl;
        }
    }
    int lim = (N_NODES - n0) * N_REL;
    if (lim > BK_NODES * N_REL) lim = BK_NODES * N_REL;
    for (int i = t; i < lim; i += 256) {
        int cc = h2[i];
        invcnt[(size_t)n0 * N_REL + i] = 1.0f / (float)(cc > 1 ? cc : 1);
    }
    __syncthreads();

    for (int s = 0; s < NSUB; s++) {
        int cs = scnt[s];
        const int* rp = rec + rbase + s * SUB_CAP;
        for (int i = t; i < cs; i += 256) {
            int q = rp[i];
            int p = atomicAdd(&lcur[q >> 20], 1);
            if (p < BK_CAP)                       // defensive
                sorted[p] = q & 0xFFFFF;          // strip ldst: (src<<3)|rel
        }
    }
    __syncthreads();

    int total = s_total;
    if (total > BK_CAP) total = BK_CAP;           // defensive
    for (int i = t; i < total; i += 256) rec[rbase + i] = sorted[i];
}

// ---------------- gather aggregation: one HALF-wave (32 lanes) per node ----
// fully predicated 8-deep loop (no serial dependent tail); fused epilogue.
__global__ __launch_bounds__(256) void gather_agg(const int* __restrict__ rec,
                                                  const int* __restrict__ offs,
                                                  const int* __restrict__ deg,
                                                  const float* __restrict__ invcnt,
                                                  const float* __restrict__ bias,
                                                  const unsigned short* __restrict__ Hm,
                                                  const float* __restrict__ Hr,
                                                  const int* __restrict__ batch,
                                                  float* __restrict__ pooled) {
    __shared__ float lpool[N_GRAPHS][HID];
    const int t = threadIdx.x;
    for (int i = t; i < N_GRAPHS * HID; i += 256) ((float*)lpool)[i] = 0.f;
    __syncthreads();

    const int d = blockIdx.x * 8 + (t >> 5);   // 12500*8 == N_NODES exactly
    const int c = t & 31;

    int dg = deg[d];
    int start = offs[d];
    int end = start + dg;

    float acc = 0.f;
    // predicated 8-deep: rec reads beyond end are address-safe (bucket slack
    // within rec buffer); masked records forced to q=0, weight=0.
    for (int i = start; i < end; i += 8) {
        int q[8];
        float h[8], w[8];
        #pragma unroll
        for (int j = 0; j < 8; j++) {
            bool ok = (i + j) < end;
            int qq = rec[i + j];
            q[j] = ok ? qq : 0;
            w[j] = ok ? 1.f : 0.f;
        }
        #pragma unroll
        for (int j = 0; j < 8; j++)
            h[j] = bf2f(Hm[(size_t)((q[j] >> 3) & 0x1FFFF) * MC + (q[j] & 7) * HID + c]);
        #pragma unroll
        for (int j = 0; j < 8; j++)
            acc = fmaf(h[j], w[j] * invcnt[d * N_REL + (q[j] & 7)], acc);
    }

    float v = Hr[(size_t)d * HID + c] + bias[c] + acc;
    v = fmaxf(v, 0.f);
    atomicAdd(&lpool[batch[d]][c], v);
    __syncthreads();

    float* pp = pooled + (size_t)(blockIdx.x & (NPOOL - 1)) * N_GRAPHS * HID;
    for (int i2 = t; i2 < N_GRAPHS * HID; i2 += 256) {
        float v2 = ((float*)lpool)[i2];
        if (v2 != 0.f) atomicAdd(&pp[i2], v2);
    }
}

// ---------------- final FC (sums the NPOOL partial slices) ----------
__global__ void fc_kernel(const float* __restrict__ pooled, const float* __restrict__ fc_w,
                          const float* __restrict__ fc_b, float* __restrict__ out) {
    int t = threadIdx.x;
    if (t >= N_GRAPHS * OUT_DIM) return;
    int g = t >> 2, o = t & 3;
    float acc = fc_b[o];
    #pragma unroll
    for (int c = 0; c < HID; c++) {
        float p = 0.f;
        #pragma unroll
        for (int k = 0; k < NPOOL; k++)
            p += pooled[(size_t)(k * N_GRAPHS + g) * HID + c];
        acc += p * fc_w[c * OUT_DIM + o];
    }
    out[t] = acc;
}

extern "C" void kernel_launch(void* const* d_in, const int* in_sizes, int n_in,
                              void* d_out, int out_size, void* d_ws, size_t ws_size,
                              hipStream_t stream) {
    const float* node_x  = (const float*)d_in[0];
    const int*   edge_ix = (const int*)d_in[1];
    const int*   e_attr  = (const int*)d_in[2];
    const int*   batch   = (const int*)d_in[3];
    const float* W_rel   = (const float*)d_in[4];
    const float* W_root  = (const float*)d_in[5];
    const float* bias    = (const float*)d_in[6];
    const float* fc_w    = (const float*)d_in[7];
    const float* fc_b    = (const float*)d_in[8];
    float* out = (float*)d_out;

    char* ws = (char*)d_ws;
    size_t off = 0;
    auto alloc = [&](size_t bytes) {
        char* p = ws + off;
        off += (bytes + 255) & ~(size_t)255;
        return p;
    };
    unsigned short* Wbf = (unsigned short*)alloc((size_t)KPAD * NC * 2);   // 256 KB
    float* Hr      = (float*)alloc((size_t)N_NODES * HID * 4);             // 12.8 MB
    unsigned short* Hm = (unsigned short*)alloc((size_t)N_NODES * MC * 2); // 44.8 MB
    int*   rec     = (int*)  alloc((size_t)N_BUCKETS * BK_CAP * 4);        // 12.8 MB
    int*   bcur    = (int*)  alloc((size_t)N_BUCKETS * NSUB * 4);          // 50 KB
    int*   deg     = (int*)  alloc((size_t)N_NODES * 4);
    int*   offsb   = (int*)  alloc((size_t)N_NODES * 4);
    float* invcnt  = (float*)alloc((size_t)N_NODES * N_REL * 4);           // 2.8 MB
    float* pooled  = (float*)alloc((size_t)NPOOL * N_GRAPHS * HID * 4);    // 16 KB
    (void)ws_size; (void)in_sizes; (void)n_in; (void)out_size;

    const int* src = edge_ix;
    const int* dst = edge_ix + N_EDGES;

    hipMemsetAsync(pooled, 0, (size_t)NPOOL * N_GRAPHS * HID * 4, stream);

    build_wbf<<<(KPAD * NC + 255) / 256, 256, 0, stream>>>(W_root, W_rel, Wbf);

    init_bcur<<<(N_BUCKETS * NSUB + 255) / 256, 256, 0, stream>>>(bcur);
    bin_edges<<<(N_EDGES + 255) / 256, 256, 0, stream>>>(src, dst, e_attr, bcur, rec);
    bucket_sort<<<N_BUCKETS, 256, 0, stream>>>(rec, bcur, deg, offsb, invcnt);

    gemm_mfma<<<(N_NODES + 63) / 64, 256, 0, stream>>>(node_x, (const uint4*)Wbf, Hr, Hm);

    gather_agg<<<(N_NODES + 7) / 8, 256, 0, stream>>>(rec, offsb, deg, invcnt,
                                                      bias, Hm, Hr, batch, pooled);

    fc_kernel<<<1, 64, 0, stream>>>(pooled, fc_w, fc_b, out);
}

// Round 6
// 425.769 us; speedup vs baseline: 1.1757x; 1.1757x over previous
//
#include <hip/hip_runtime.h>

#define N_NODES 100000
#define N_EDGES 1600000
#define IN_DIM 500
#define HID 32
#define N_REL 7
#define OUT_DIM 4
#define N_GRAPHS 16
#define NC 256      // (N_REL + 1) * HID: [root | rel0..rel6]
#define MC 224      // message cols (N_REL * HID)
#define KPAD 512

// dst-bucketing: 64 nodes/bucket; 8 sub-cursors/bucket (indexed by XCD slot)
#define BK_SHIFT 6
#define BK_NODES 64
#define N_BUCKETS ((N_NODES + BK_NODES - 1) / BK_NODES)   // 1563
#define NSUB 8
#define SUB_CAP 256
#define BK_CAP (NSUB * SUB_CAP)  // 2048
#define NPOOL 8

// merged gemm+bin grid: groups of 8 consecutive blocks (one per XCD);
// every 5th group is gemm (1563:6250 ~ 1:4), so both roles hit all XCDs.
#define GEMM_BLOCKS ((N_NODES + 63) / 64)        // 1563
#define BIN_BLOCKS  ((N_EDGES + 255) / 256)      // 6250
#define N_GROUPS 978                             // 196 gemm + 782 bin groups
#define GRID_MERGED (N_GROUPS * 8)               // 7824

typedef __attribute__((ext_vector_type(8))) short bf16x8;
typedef __attribute__((ext_vector_type(4))) float f32x4;

__device__ inline unsigned short f2bf(float f) {
    unsigned u = __float_as_uint(f);
    unsigned r = (u + 0x7FFFu + ((u >> 16) & 1u)) >> 16;
    return (unsigned short)r;
}
__device__ inline float bf2f(unsigned short b) {
    return __uint_as_float((unsigned)b << 16);
}

// ---------------- build Wbf + init bcur + zero pooled (fused tiny setup) ---
__global__ void build_wbf(const float* __restrict__ W_root,
                          const float* __restrict__ W_rel,
                          unsigned short* __restrict__ Wbf,
                          int* __restrict__ bcur,
                          float* __restrict__ pooled) {
    int idx = blockIdx.x * blockDim.x + threadIdx.x;   // 0 .. KPAD*NC-1
    if (idx < N_BUCKETS * NSUB) bcur[idx] = idx * SUB_CAP;
    if (idx < NPOOL * N_GRAPHS * HID) pooled[idx] = 0.f;
    if (idx >= KPAD * NC) return;
    int kk = idx >> 8;
    int n = idx & 255;
    float v = 0.f;
    if (kk < IN_DIM) {
        if (n < HID) v = W_root[kk * HID + n];
        else {
            int r = (n >> 5) - 1;
            v = W_rel[((size_t)r * IN_DIM + kk) * HID + (n & 31)];
        }
    }
    int ks = kk >> 5, q = (kk >> 3) & 3, j = kk & 7;
    Wbf[(size_t)((((ks << 2) + q) << 8) + n) * 8 + j] = f2bf(v);
}

// ---------------- merged: MFMA GEMM (round-4 body) + bin_edges -------------
// gemm: [Hr fp32 | Hm bf16] = bf16(A) @ Wbf, 64x256 tile, 4 waves.
// bin: scatter edges into (bucket, xcd-slot) sub-regions of rec.
__global__ __launch_bounds__(256, 4) void gemm_bin(const float* __restrict__ A,
                                                   const uint4* __restrict__ Wbf,
                                                   float* __restrict__ Hr,
                                                   unsigned short* __restrict__ Hm,
                                                   const int* __restrict__ src,
                                                   const int* __restrict__ dst,
                                                   const int* __restrict__ attr,
                                                   int* __restrict__ bcur,
                                                   int* __restrict__ rec) {
    const int grp = blockIdx.x >> 3, j8 = blockIdx.x & 7;

    if (grp % 5 != 0) {
        // ---------------- bin_edges role ----------------
        int bb = (grp - grp / 5 - 1) * 8 + j8;
        if (bb >= BIN_BLOCKS) return;
        int e = bb * 256 + threadIdx.x;
        if (e >= N_EDGES) return;
        int d = dst[e];
        int cur = (d >> BK_SHIFT) * NSUB + j8;   // j8 == XCD slot
        int p = atomicAdd(&bcur[cur], 1);
        if (p < (cur + 1) * SUB_CAP)   // overflow guard (prob ~ 0)
            rec[p] = ((d & (BK_NODES - 1)) << 20) | (src[e] << 3) | attr[e];
        return;
    }

    // ---------------- gemm role (round-4 structure, known-good) ----------------
    int bid = (grp / 5) * 8 + j8;
    if (bid >= GEMM_BLOCKS) return;

    __shared__ uint4 Alds[32 * 64];   // 32 KB: entry(ksq_local, row^swz)

    const int tid = threadIdx.x;
    const int wave = tid >> 6, lane = tid & 63;
    const int l16 = lane & 15, q = lane >> 4;
    const int row0 = bid * 64;
    const int wn = wave * 64;

    int rows_valid = N_NODES - row0; if (rows_valid > 64) rows_valid = 64;
    const float4* Ablk4 = (const float4*)(A + (size_t)row0 * IN_DIM);

    f32x4 acc[4][4];
    #pragma unroll
    for (int mt = 0; mt < 4; mt++)
        #pragma unroll
        for (int nt = 0; nt < 4; nt++)
            #pragma unroll
            for (int r = 0; r < 4; r++) acc[mt][nt][r] = 0.f;

    for (int half = 0; half < 2; half++) {
        if (half) __syncthreads();   // prev compute done before LDS overwrite
        // ---- stage: 64 rows x 256 k ----
        #pragma unroll 4
        for (int it = 0; it < 16; it++) {
            int idx = it * 256 + tid;
            int row = idx >> 6, slot = idx & 63;
            int k = half * 256 + slot * 4;
            float4 v = make_float4(0.f, 0.f, 0.f, 0.f);
            if (row < rows_valid && k < IN_DIM)
                v = Ablk4[row * 125 + (k >> 2)];
            int ksq = slot >> 1;                       // local 0..31
            int e = (ksq << 6) | ((row ^ ksq) & 63);
            ushort4 b;
            b.x = f2bf(v.x); b.y = f2bf(v.y); b.z = f2bf(v.z); b.w = f2bf(v.w);
            *(ushort4*)((unsigned short*)&Alds[e] + (slot & 1) * 4) = b;
        }
        __syncthreads();
        // ---- compute 8 k-steps ----
        #pragma unroll 2
        for (int ksl = 0; ksl < 8; ksl++) {
            int ksq_l = ksl * 4 + q;
            int ksq_g = half * 32 + ksq_l;
            bf16x8 bfr[4], afr[4];
            #pragma unroll
            for (int nt = 0; nt < 4; nt++) {
                uint4 t = Wbf[(size_t)(ksq_g << 8) + wn + nt * 16 + l16];
                bfr[nt] = *(bf16x8*)&t;
            }
            #pragma unroll
            for (int mt = 0; mt < 4; mt++)
                afr[mt] = *(const bf16x8*)&Alds[(ksq_l << 6) | (((mt * 16 + l16) ^ ksq_l) & 63)];
            #pragma unroll
            for (int mt = 0; mt < 4; mt++)
                #pragma unroll
                for (int nt = 0; nt < 4; nt++)
                    acc[mt][nt] = __builtin_amdgcn_mfma_f32_16x16x32_bf16(
                        afr[mt], bfr[nt], acc[mt][nt], 0, 0, 0);
        }
    }

    // ---- store: C/D layout col=lane&15, row=(lane>>4)*4+reg ----
    #pragma unroll
    for (int mt = 0; mt < 4; mt++) {
        int rbase = row0 + mt * 16 + q * 4;
        #pragma unroll
        for (int r = 0; r < 4; r++) {
            int row = rbase + r;
            if (row < N_NODES) {
                #pragma unroll
                for (int nt = 0; nt < 4; nt++) {
                    int col = wn + nt * 16 + l16;
                    float v = acc[mt][nt][r];
                    if (wave == 0 && nt < 2)            // col < 32: root slice
                        Hr[(size_t)row * HID + col] = v;
                    else
                        Hm[(size_t)row * MC + (col - HID)] = f2bf(v);
                }
            }
        }
    }
}

// ---------------- per-bucket LDS counting sort + deg/offs/invcnt -----------
__global__ __launch_bounds__(256) void bucket_sort(int* __restrict__ rec,
                                                   const int* __restrict__ bcur,
                                                   int* __restrict__ deg,
                                                   int* __restrict__ offs,
                                                   float* __restrict__ invcnt) {
    __shared__ int h2[BK_NODES * N_REL];   // per-(node,rel) counts
    __shared__ int lcur[BK_NODES];         // scatter cursors
    __shared__ int sorted[BK_CAP];         // 8 KB
    __shared__ int scnt[NSUB];
    __shared__ int s_total;

    const int b = blockIdx.x, t = threadIdx.x;
    const int n0 = b << BK_SHIFT;
    const size_t rbase = (size_t)b * BK_CAP;

    for (int i = t; i < BK_NODES * N_REL; i += 256) h2[i] = 0;
    if (t < NSUB) {
        int c = bcur[b * NSUB + t] - (b * NSUB + t) * SUB_CAP;
        scnt[t] = c < SUB_CAP ? c : SUB_CAP;
    }
    __syncthreads();

    for (int s = 0; s < NSUB; s++) {
        int cs = scnt[s];
        const int* rp = rec + rbase + s * SUB_CAP;
        for (int i = t; i < cs; i += 256) {
            int q = rp[i];
            atomicAdd(&h2[(q >> 20) * N_REL + (q & 7)], 1);
        }
    }
    __syncthreads();

    if (t < BK_NODES) {       // wave 0: per-node totals + exclusive scan
        int tot = 0;
        #pragma unroll
        for (int r = 0; r < N_REL; r++) tot += h2[t * N_REL + r];
        int incl = tot;
        #pragma unroll
        for (int off = 1; off < BK_NODES; off <<= 1) {
            int y = __shfl_up(incl, off, 64);
            if (t >= off) incl += y;
        }
        int excl = incl - tot;
        lcur[t] = excl;
        if (t == BK_NODES - 1) s_total = incl;
        int n = n0 + t;
        if (n < N_NODES) {
            deg[n] = tot;
            offs[n] = (int)rbase + excl;
        }
    }
    int lim = (N_NODES - n0) * N_REL;
    if (lim > BK_NODES * N_REL) lim = BK_NODES * N_REL;
    for (int i = t; i < lim; i += 256) {
        int cc = h2[i];
        invcnt[(size_t)n0 * N_REL + i] = 1.0f / (float)(cc > 1 ? cc : 1);
    }
    __syncthreads();

    for (int s = 0; s < NSUB; s++) {
        int cs = scnt[s];
        const int* rp = rec + rbase + s * SUB_CAP;
        for (int i = t; i < cs; i += 256) {
            int q = rp[i];
            int p = atomicAdd(&lcur[q >> 20], 1);
            if (p < BK_CAP)                       // defensive
                sorted[p] = q & 0xFFFFF;          // strip ldst: (src<<3)|rel
        }
    }
    __syncthreads();

    int total = s_total;
    if (total > BK_CAP) total = BK_CAP;           // defensive
    for (int i = t; i < total; i += 256) rec[rbase + i] = sorted[i];
}

// ---------------- gather aggregation: one HALF-wave (32 lanes) per node ----
// fully predicated 8-deep loop; fused relu+bias+graph pooling.
__global__ __launch_bounds__(256) void gather_agg(const int* __restrict__ rec,
                                                  const int* __restrict__ offs,
                                                  const int* __restrict__ deg,
                                                  const float* __restrict__ invcnt,
                                                  const float* __restrict__ bias,
                                                  const unsigned short* __restrict__ Hm,
                                                  const float* __restrict__ Hr,
                                                  const int* __restrict__ batch,
                                                  float* __restrict__ pooled) {
    __shared__ float lpool[N_GRAPHS][HID];
    const int t = threadIdx.x;
    for (int i = t; i < N_GRAPHS * HID; i += 256) ((float*)lpool)[i] = 0.f;
    __syncthreads();

    const int d = blockIdx.x * 8 + (t >> 5);   // 12500*8 == N_NODES exactly
    const int c = t & 31;

    int dg = deg[d];
    int start = offs[d];
    int end = start + dg;

    float acc = 0.f;
    // predicated 8-deep: rec reads beyond end stay inside ws (bucket slack);
    // masked records forced to q=0, weight=0.
    for (int i = start; i < end; i += 8) {
        int q[8];
        float h[8], w[8];
        #pragma unroll
        for (int j = 0; j < 8; j++) {
            bool ok = (i + j) < end;
            int qq = rec[i + j];
            q[j] = ok ? qq : 0;
            w[j] = ok ? 1.f : 0.f;
        }
        #pragma unroll
        for (int j = 0; j < 8; j++)
            h[j] = bf2f(Hm[(size_t)((q[j] >> 3) & 0x1FFFF) * MC + (q[j] & 7) * HID + c]);
        #pragma unroll
        for (int j = 0; j < 8; j++)
            acc = fmaf(h[j], w[j] * invcnt[d * N_REL + (q[j] & 7)], acc);
    }

    float v = Hr[(size_t)d * HID + c] + bias[c] + acc;
    v = fmaxf(v, 0.f);
    atomicAdd(&lpool[batch[d]][c], v);
    __syncthreads();

    float* pp = pooled + (size_t)(blockIdx.x & (NPOOL - 1)) * N_GRAPHS * HID;
    for (int i2 = t; i2 < N_GRAPHS * HID; i2 += 256) {
        float v2 = ((float*)lpool)[i2];
        if (v2 != 0.f) atomicAdd(&pp[i2], v2);
    }
}

// ---------------- final FC (sums the NPOOL partial slices) ----------
__global__ void fc_kernel(const float* __restrict__ pooled, const float* __restrict__ fc_w,
                          const float* __restrict__ fc_b, float* __restrict__ out) {
    int t = threadIdx.x;
    if (t >= N_GRAPHS * OUT_DIM) return;
    int g = t >> 2, o = t & 3;
    float acc = fc_b[o];
    #pragma unroll
    for (int c = 0; c < HID; c++) {
        float p = 0.f;
        #pragma unroll
        for (int k = 0; k < NPOOL; k++)
            p += pooled[(size_t)(k * N_GRAPHS + g) * HID + c];
        acc += p * fc_w[c * OUT_DIM + o];
    }
    out[t] = acc;
}

extern "C" void kernel_launch(void* const* d_in, const int* in_sizes, int n_in,
                              void* d_out, int out_size, void* d_ws, size_t ws_size,
                              hipStream_t stream) {
    const float* node_x  = (const float*)d_in[0];
    const int*   edge_ix = (const int*)d_in[1];
    const int*   e_attr  = (const int*)d_in[2];
    const int*   batch   = (const int*)d_in[3];
    const float* W_rel   = (const float*)d_in[4];
    const float* W_root  = (const float*)d_in[5];
    const float* bias    = (const float*)d_in[6];
    const float* fc_w    = (const float*)d_in[7];
    const float* fc_b    = (const float*)d_in[8];
    float* out = (float*)d_out;

    char* ws = (char*)d_ws;
    size_t off = 0;
    auto alloc = [&](size_t bytes) {
        char* p = ws + off;
        off += (bytes + 255) & ~(size_t)255;
        return p;
    };
    unsigned short* Wbf = (unsigned short*)alloc((size_t)KPAD * NC * 2);   // 256 KB
    float* Hr      = (float*)alloc((size_t)N_NODES * HID * 4);             // 12.8 MB
    unsigned short* Hm = (unsigned short*)alloc((size_t)N_NODES * MC * 2); // 44.8 MB
    int*   rec     = (int*)  alloc((size_t)N_BUCKETS * BK_CAP * 4);        // 12.8 MB
    int*   bcur    = (int*)  alloc((size_t)N_BUCKETS * NSUB * 4);          // 50 KB
    int*   deg     = (int*)  alloc((size_t)N_NODES * 4);
    int*   offsb   = (int*)  alloc((size_t)N_NODES * 4);
    float* invcnt  = (float*)alloc((size_t)N_NODES * N_REL * 4);           // 2.8 MB
    float* pooled  = (float*)alloc((size_t)NPOOL * N_GRAPHS * HID * 4);    // 16 KB
    (void)ws_size; (void)in_sizes; (void)n_in; (void)out_size;

    const int* src = edge_ix;
    const int* dst = edge_ix + N_EDGES;

    // setup: Wbf build + bcur init + pooled zero (one launch)
    build_wbf<<<(KPAD * NC + 255) / 256, 256, 0, stream>>>(W_root, W_rel, Wbf,
                                                           bcur, pooled);

    // gemm overlapped with edge binning (independent work, one launch)
    gemm_bin<<<GRID_MERGED, 256, 0, stream>>>(node_x, (const uint4*)Wbf, Hr, Hm,
                                              src, dst, e_attr, bcur, rec);

    bucket_sort<<<N_BUCKETS, 256, 0, stream>>>(rec, bcur, deg, offsb, invcnt);

    gather_agg<<<(N_NODES + 7) / 8, 256, 0, stream>>>(rec, offsb, deg, invcnt,
                                                      bias, Hm, Hr, batch, pooled);

    fc_kernel<<<1, 64, 0, stream>>>(pooled, fc_w, fc_b, out);
}